// Round 4
// baseline (1812.616 us; speedup 1.0000x reference)
//
#include <hip/hip_runtime.h>
#include <hip/hip_bf16.h>
#include <stdint.h>

// Problem dims
#define Bn 16384
#define Cn 512
#define Dn 512
#define Hn 1024

// ---------------------------------------------------------------------------
// JAX threefry2x32 (20 rounds), PARTITIONABLE semantics (modern JAX default):
//   split(key,n)[i] = both output words of counter (0, i)   [== fold_in(key,i)]
//   random_bits(key,32,N)[j] = w0 ^ w1 of counter (0, j)
// ---------------------------------------------------------------------------
__device__ __forceinline__ uint32_t rotl32(uint32_t v, int s) {
  return (v << s) | (v >> (32 - s));
}

__device__ __forceinline__ void threefry2x32(uint32_t k0, uint32_t k1,
                                             uint32_t x0, uint32_t x1,
                                             uint32_t& o0, uint32_t& o1) {
  const uint32_t k2 = k0 ^ k1 ^ 0x1BD11BDAu;
  x0 += k0; x1 += k1;
#define TFR(r) { x0 += x1; x1 = rotl32(x1, (r)); x1 ^= x0; }
  TFR(13) TFR(15) TFR(26) TFR(6)   x0 += k1; x1 += k2 + 1u;
  TFR(17) TFR(29) TFR(16) TFR(24)  x0 += k2; x1 += k0 + 2u;
  TFR(13) TFR(15) TFR(26) TFR(6)   x0 += k0; x1 += k1 + 3u;
  TFR(17) TFR(29) TFR(16) TFR(24)  x0 += k1; x1 += k2 + 4u;
  TFR(13) TFR(15) TFR(26) TFR(6)   x0 += k2; x1 += k0 + 5u;
#undef TFR
  o0 = x0; o1 = x1;
}

// bits -> uniform[-0.99999994, 1) -> sqrt(2)*erfinv (XLA/Giles f32 polynomial)
__device__ __forceinline__ float bits_to_normal(uint32_t bits) {
  float f = __uint_as_float((bits >> 9) | 0x3f800000u) - 1.0f;  // [0,1)
  float x = f * 2.0f - 0x1.fffffep-1f;  // (maxval-minval) rounds to 2.0f
  float w = -__logf(1.0f - x * x);
  float p;
  if (w < 5.0f) {
    w -= 2.5f;
    p =            2.81022636e-08f;
    p = fmaf(p, w, 3.43273939e-07f);
    p = fmaf(p, w, -3.5233877e-06f);
    p = fmaf(p, w, -4.39150654e-06f);
    p = fmaf(p, w, 0.00021858087f);
    p = fmaf(p, w, -0.00125372503f);
    p = fmaf(p, w, -0.00417768164f);
    p = fmaf(p, w, 0.246640727f);
    p = fmaf(p, w, 1.50140941f);
  } else {
    w = sqrtf(w) - 3.0f;
    p =            -0.000200214257f;
    p = fmaf(p, w, 0.000100950558f);
    p = fmaf(p, w, 0.00134934322f);
    p = fmaf(p, w, -0.00367342844f);
    p = fmaf(p, w, 0.00573950773f);
    p = fmaf(p, w, -0.0076224613f);
    p = fmaf(p, w, 0.00943887047f);
    p = fmaf(p, w, 1.00167406f);
    p = fmaf(p, w, 2.83297682f);
  }
  return 0x1.6a09e6p+0f * (p * x);  // sqrt(2) * erfinv(x)
}

// 32-step Langevin chain on latent u (u0=0), returns sigmoid(-u) (TAU=1)
__device__ __forceinline__ float langevin_gate(float e, const uint32_t* __restrict__ keys,
                                               uint32_t j) {
  float u = 0.0f;
#pragma unroll 1
  for (int t = 0; t < 32; ++t) {
    uint32_t o0, o1;
    threefry2x32(keys[2 * t], keys[2 * t + 1], 0u, j, o0, o1);
    float n = bits_to_normal(o0 ^ o1);
    u = (u - 0.05f * (u + e)) + 0.1f * n;  // u -= STEP*(u+e); u += NOISE*n
  }
  return 1.0f / (1.0f + __expf(u));  // sigmoid(-u)
}

// keys[0..63] = static-mask step keys; keys[64..127] = dynamic-gate step keys
__global__ void k_setup_keys(uint32_t* __restrict__ keys) {
  if (threadIdx.x != 0 || blockIdx.x != 0) return;
  uint32_t k1w0, k1w1, k2w0, k2w1;
  threefry2x32(0u, 42u, 0u, 0u, k1w0, k1w1);  // split(key(42))[0]
  threefry2x32(0u, 42u, 0u, 1u, k2w0, k2w1);  // split(key(42))[1]
  for (uint32_t t = 0; t < 32; ++t) {
    uint32_t w0, w1;
    threefry2x32(k1w0, k1w1, 0u, t, w0, w1);
    keys[2 * t] = w0; keys[2 * t + 1] = w1;
    threefry2x32(k2w0, k2w1, 0u, t, w0, w1);
    keys[64 + 2 * t] = w0; keys[64 + 2 * t + 1] = w1;
  }
}

// comps[j] = |vc[j]| * langevin_gate(e_sp[j]),  j in [0, C*D)
__global__ __launch_bounds__(256) void k_static_mask(
    const float* __restrict__ vc, const float* __restrict__ e_sp,
    const uint32_t* __restrict__ keys, float* __restrict__ comps) {
  int j = blockIdx.x * 256 + threadIdx.x;
  comps[j] = fabsf(vc[j]) * langevin_gate(e_sp[j], keys, (uint32_t)j);
}

// in-place: eg[j] (= e_dyn) -> gate[j],  j in [0, B*C)
__global__ __launch_bounds__(256) void k_dyn_gate(
    float* __restrict__ eg, const uint32_t* __restrict__ keys) {
  int j = blockIdx.x * 256 + threadIdx.x;
  eg[j] = langevin_gate(eg[j], keys, (uint32_t)j);
}

// ---------------------------------------------------------------------------
// fp32 tiled GEMM: C[M,N] = epi(A[M,K] @ W[K,N]).  64x64 tile, BK=16,
// 256 threads (16x16), 4x4 accum per thread.  FP32 OUTPUT (reference dtype).
// ---------------------------------------------------------------------------
template <bool RELU, bool HASBIAS, bool GATEMUL>
__global__ __launch_bounds__(256) void k_gemm(
    const float* __restrict__ A, const float* __restrict__ W,
    const float* __restrict__ bias, const float* __restrict__ gate,
    float* __restrict__ Cout, int M, int N, int K) {
  __shared__ float As[64][20];
  __shared__ float Bs[16][64];

  const int tx = threadIdx.x, ty = threadIdx.y;
  const int t = ty * 16 + tx;
  const int row0 = blockIdx.y * 64, col0 = blockIdx.x * 64;

  const int arow = t >> 2, acol = (t & 3) << 2;   // A tile: 64 rows x 16 k
  const int brow = t >> 4, bcol = (t & 15) << 2;  // W tile: 16 k x 64 cols

  const float* Aptr = A + (size_t)(row0 + arow) * K + acol;
  const float* Wptr = W + (size_t)brow * N + col0 + bcol;

  float acc[4][4] = {};

  for (int kt = 0; kt < K; kt += 16) {
    float4 av = *(const float4*)(Aptr + kt);
    float4 bv = *(const float4*)(Wptr + (size_t)kt * N);
    *(float4*)&As[arow][acol] = av;
    *(float4*)&Bs[brow][bcol] = bv;
    __syncthreads();
#pragma unroll
    for (int kk = 0; kk < 16; ++kk) {
      float a0 = As[ty * 4 + 0][kk];
      float a1 = As[ty * 4 + 1][kk];
      float a2 = As[ty * 4 + 2][kk];
      float a3 = As[ty * 4 + 3][kk];
      float4 b = *(const float4*)&Bs[kk][tx * 4];
      acc[0][0] = fmaf(a0, b.x, acc[0][0]); acc[0][1] = fmaf(a0, b.y, acc[0][1]);
      acc[0][2] = fmaf(a0, b.z, acc[0][2]); acc[0][3] = fmaf(a0, b.w, acc[0][3]);
      acc[1][0] = fmaf(a1, b.x, acc[1][0]); acc[1][1] = fmaf(a1, b.y, acc[1][1]);
      acc[1][2] = fmaf(a1, b.z, acc[1][2]); acc[1][3] = fmaf(a1, b.w, acc[1][3]);
      acc[2][0] = fmaf(a2, b.x, acc[2][0]); acc[2][1] = fmaf(a2, b.y, acc[2][1]);
      acc[2][2] = fmaf(a2, b.z, acc[2][2]); acc[2][3] = fmaf(a2, b.w, acc[2][3]);
      acc[3][0] = fmaf(a3, b.x, acc[3][0]); acc[3][1] = fmaf(a3, b.y, acc[3][1]);
      acc[3][2] = fmaf(a3, b.z, acc[3][2]); acc[3][3] = fmaf(a3, b.w, acc[3][3]);
    }
    __syncthreads();
  }

#pragma unroll
  for (int i = 0; i < 4; ++i) {
    const int row = row0 + ty * 4 + i;
#pragma unroll
    for (int jj = 0; jj < 4; ++jj) {
      const int col = col0 + tx * 4 + jj;
      float c = acc[i][jj];
      if (HASBIAS) c += bias[col];
      if (RELU) c = fmaxf(c, 0.0f);
      if (GATEMUL) c *= gate[(size_t)row * N + col];
      Cout[(size_t)row * N + col] = c;
    }
  }
}

// ---------------------------------------------------------------------------
extern "C" void kernel_launch(void* const* d_in, const int* in_sizes, int n_in,
                              void* d_out, int out_size, void* d_ws, size_t ws_size,
                              hipStream_t stream) {
  const float* x    = (const float*)d_in[0];
  const float* vc   = (const float*)d_in[1];
  const float* e_sp = (const float*)d_in[2];
  const float* W1e  = (const float*)d_in[3];
  const float* b1e  = (const float*)d_in[4];
  const float* W2e  = (const float*)d_in[5];
  const float* b2e  = (const float*)d_in[6];
  const float* W1r  = (const float*)d_in[7];
  const float* b1r  = (const float*)d_in[8];
  const float* W2r  = (const float*)d_in[9];
  const float* b2r  = (const float*)d_in[10];
  float* out = (float*)d_out;  // fp32 — reference output dtype

  // Workspace layout (bytes):
  //   [0,512)       threefry step keys (128 u32)
  //   [4096, +1MB)  comps (C*D f32)
  //   [o_h, +64MB)  h / hr (B*H f32, reused)
  //   [o_eg, +32MB) e_dyn -> gate -> conc (B*C f32, in-place)
  char* ws = (char*)d_ws;
  uint32_t* keys = (uint32_t*)ws;
  float* comps = (float*)(ws + 4096);
  float* h  = (float*)(ws + 4096 + ((size_t)Cn * Dn * 4));
  float* eg = (float*)(ws + 4096 + ((size_t)Cn * Dn * 4) + ((size_t)Bn * Hn * 4));

  const dim3 blk(16, 16);

  // 1. derive threefry step keys (partitionable semantics)
  k_setup_keys<<<1, 64, 0, stream>>>(keys);
  // 2. static component mask: comps = |vc| * p_sp
  k_static_mask<<<(Cn * Dn) / 256, 256, 0, stream>>>(vc, e_sp, keys, comps);
  // 3. h = relu(x @ W1e + b1e)
  k_gemm<true, true, false><<<dim3(Hn / 64, Bn / 64), blk, 0, stream>>>(
      x, W1e, b1e, nullptr, h, Bn, Hn, Dn);
  // 4. e_dyn = h @ W2e + b2e
  k_gemm<false, true, false><<<dim3(Cn / 64, Bn / 64), blk, 0, stream>>>(
      h, W2e, b2e, nullptr, eg, Bn, Cn, Hn);
  // 5. gate = langevin(e_dyn) in-place
  k_dyn_gate<<<((size_t)Bn * Cn) / 256, 256, 0, stream>>>(eg, keys + 64);
  // 6. hr = relu(x @ W1r + b1r)  (reuse h buffer)
  k_gemm<true, true, false><<<dim3(Hn / 64, Bn / 64), blk, 0, stream>>>(
      x, W1r, b1r, nullptr, h, Bn, Hn, Dn);
  // 7. conc = (hr @ W2r + b2r) * gate, in-place into eg
  k_gemm<false, true, true><<<dim3(Cn / 64, Bn / 64), blk, 0, stream>>>(
      h, W2r, b2r, eg, eg, Bn, Cn, Hn);
  // 8. out = conc @ comps  (fp32 store)
  k_gemm<false, false, false><<<dim3(Dn / 64, Bn / 64), blk, 0, stream>>>(
      eg, comps, nullptr, nullptr, out, Bn, Dn, Cn);
}

// Round 5
// 891.456 us; speedup vs baseline: 2.0333x; 2.0333x over previous
//
#include <hip/hip_runtime.h>
#include <hip/hip_bf16.h>
#include <stdint.h>

// Problem dims
#define Bn 16384
#define Cn 512
#define Dn 512
#define Hn 1024

typedef __attribute__((ext_vector_type(8))) short bf16x8;   // 8 bf16 (4 VGPRs)
typedef __attribute__((ext_vector_type(4))) float f32x4;    // MFMA accum

// f32 -> bf16 RTNE (manual; inputs are finite)
__device__ __forceinline__ ushort f2bf(float f) {
  uint32_t u = __float_as_uint(f);
  return (ushort)((u + 0x7fffu + ((u >> 16) & 1u)) >> 16);
}

// ---------------------------------------------------------------------------
// JAX threefry2x32 (20 rounds), PARTITIONABLE semantics (verified round 4)
// ---------------------------------------------------------------------------
__device__ __forceinline__ uint32_t rotl32(uint32_t v, int s) {
  return (v << s) | (v >> (32 - s));
}

__device__ __forceinline__ void threefry2x32(uint32_t k0, uint32_t k1,
                                             uint32_t x0, uint32_t x1,
                                             uint32_t& o0, uint32_t& o1) {
  const uint32_t k2 = k0 ^ k1 ^ 0x1BD11BDAu;
  x0 += k0; x1 += k1;
#define TFR(r) { x0 += x1; x1 = rotl32(x1, (r)); x1 ^= x0; }
  TFR(13) TFR(15) TFR(26) TFR(6)   x0 += k1; x1 += k2 + 1u;
  TFR(17) TFR(29) TFR(16) TFR(24)  x0 += k2; x1 += k0 + 2u;
  TFR(13) TFR(15) TFR(26) TFR(6)   x0 += k0; x1 += k1 + 3u;
  TFR(17) TFR(29) TFR(16) TFR(24)  x0 += k1; x1 += k2 + 4u;
  TFR(13) TFR(15) TFR(26) TFR(6)   x0 += k2; x1 += k0 + 5u;
#undef TFR
  o0 = x0; o1 = x1;
}

// bits -> uniform[-0.99999994, 1) -> sqrt(2)*erfinv (XLA/Giles f32 polynomial)
__device__ __forceinline__ float bits_to_normal(uint32_t bits) {
  float f = __uint_as_float((bits >> 9) | 0x3f800000u) - 1.0f;  // [0,1)
  float x = f * 2.0f - 0x1.fffffep-1f;
  float w = -__logf(1.0f - x * x);
  float p;
  if (w < 5.0f) {
    w -= 2.5f;
    p =            2.81022636e-08f;
    p = fmaf(p, w, 3.43273939e-07f);
    p = fmaf(p, w, -3.5233877e-06f);
    p = fmaf(p, w, -4.39150654e-06f);
    p = fmaf(p, w, 0.00021858087f);
    p = fmaf(p, w, -0.00125372503f);
    p = fmaf(p, w, -0.00417768164f);
    p = fmaf(p, w, 0.246640727f);
    p = fmaf(p, w, 1.50140941f);
  } else {
    w = sqrtf(w) - 3.0f;
    p =            -0.000200214257f;
    p = fmaf(p, w, 0.000100950558f);
    p = fmaf(p, w, 0.00134934322f);
    p = fmaf(p, w, -0.00367342844f);
    p = fmaf(p, w, 0.00573950773f);
    p = fmaf(p, w, -0.0076224613f);
    p = fmaf(p, w, 0.00943887047f);
    p = fmaf(p, w, 1.00167406f);
    p = fmaf(p, w, 2.83297682f);
  }
  return 0x1.6a09e6p+0f * (p * x);  // sqrt(2) * erfinv(x)
}

// 32-step Langevin chain on latent u (u0=0), returns sigmoid(-u) (TAU=1)
__device__ __forceinline__ float langevin_gate(float e, const uint32_t* __restrict__ keys,
                                               uint32_t j) {
  float u = 0.0f;
#pragma unroll 1
  for (int t = 0; t < 32; ++t) {
    uint32_t o0, o1;
    threefry2x32(keys[2 * t], keys[2 * t + 1], 0u, j, o0, o1);
    float n = bits_to_normal(o0 ^ o1);
    u = (u - 0.05f * (u + e)) + 0.1f * n;
  }
  return 1.0f / (1.0f + __expf(u));  // sigmoid(-u)
}

// keys[0..63] = static-mask step keys; keys[64..127] = dynamic-gate step keys
__global__ void k_setup_keys(uint32_t* __restrict__ keys) {
  if (threadIdx.x != 0 || blockIdx.x != 0) return;
  uint32_t k1w0, k1w1, k2w0, k2w1;
  threefry2x32(0u, 42u, 0u, 0u, k1w0, k1w1);
  threefry2x32(0u, 42u, 0u, 1u, k2w0, k2w1);
  for (uint32_t t = 0; t < 32; ++t) {
    uint32_t w0, w1;
    threefry2x32(k1w0, k1w1, 0u, t, w0, w1);
    keys[2 * t] = w0; keys[2 * t + 1] = w1;
    threefry2x32(k2w0, k2w1, 0u, t, w0, w1);
    keys[64 + 2 * t] = w0; keys[64 + 2 * t + 1] = w1;
  }
}

// compsT[d*C + c] = bf16(|vc[c*D+d]| * gate(e_sp[c*D+d]))   (coalesced stores)
__global__ __launch_bounds__(256) void k_static_mask(
    const float* __restrict__ vc, const float* __restrict__ e_sp,
    const uint32_t* __restrict__ keys, ushort* __restrict__ compsT) {
  uint32_t j = blockIdx.x * 256 + threadIdx.x;  // j = d*C + c
  uint32_t c = j & (Cn - 1), d = j >> 9;        // C = 512 = 2^9
  uint32_t ridx = c * Dn + d;                   // flat index in e_sp / vc
  float g = langevin_gate(e_sp[ridx], keys, ridx);
  compsT[j] = f2bf(fabsf(vc[ridx]) * g);
}

// in-place f32: eg[j] (= e_dyn) -> gate[j],  j in [0, B*C)
__global__ __launch_bounds__(256) void k_dyn_gate(
    float* __restrict__ eg, const uint32_t* __restrict__ keys) {
  uint32_t j = blockIdx.x * 256 + threadIdx.x;
  eg[j] = langevin_gate(eg[j], keys, j);
}

// ---------------------------------------------------------------------------
// Conversion kernels (fp32 inputs -> bf16 workspace)
// ---------------------------------------------------------------------------
__global__ __launch_bounds__(256) void k_cvt_x(const float* __restrict__ in,
                                               ushort* __restrict__ out) {
  int i = (blockIdx.x * 256 + threadIdx.x) * 4;
  float4 v = *(const float4*)(in + i);
  ushort4 o = make_ushort4(f2bf(v.x), f2bf(v.y), f2bf(v.z), f2bf(v.w));
  *(ushort4*)(out + i) = o;
}

// out[n*KO + k] = bf16(in[k*NO + n]);  in is [KO][NO], out is [NO][KO]
__global__ __launch_bounds__(256) void k_transpose_cvt(
    const float* __restrict__ in, ushort* __restrict__ out, int NO, int KO) {
  int o = blockIdx.x * 256 + threadIdx.x;
  int n = o / KO, k = o % KO;  // KO is a power of two
  out[o] = f2bf(in[(size_t)k * NO + n]);
}

// ---------------------------------------------------------------------------
// bf16 MFMA GEMM: C[M,N] = epi(A[M,K] @ W[K,N]),  W given transposed WT[N][K].
// 128x128 tile, BK=32, 256 threads = 4 waves (2x2 of 64x64), 4x4 16x16 MFMA
// tiles per wave, f32 accum. A-frag: A[m=lane&15][k=quad*8+j]; B-frag:
// B[k=quad*8+j][n=lane&15]; C/D: col=lane&15, row=quad*4+reg (HW-verified).
// ---------------------------------------------------------------------------
template <bool RELU, bool HASBIAS, bool GATEMUL, bool OUTBF16>
__global__ __launch_bounds__(256) void k_gemm_mfma(
    const ushort* __restrict__ A,    // [M][K] bf16
    const ushort* __restrict__ WT,   // [N][K] bf16
    const float* __restrict__ bias,  // [N] f32
    const float* __restrict__ gate,  // [M][N] f32
    void* __restrict__ Cout, int M, int N, int K) {
  __shared__ ushort As[128][40];  // +8 pad: 80 B rows -> 2-way banks (free)
  __shared__ ushort Bs[128][40];

  const int t = threadIdx.x;
  const int m0 = blockIdx.y * 128, n0 = blockIdx.x * 128;

  // staging: thread t copies 16 bf16 (32 B) of one row
  const int srow = t >> 1;
  const int skoff = (t & 1) << 4;  // 0 or 16
  const ushort* Ap = A + (size_t)(m0 + srow) * K + skoff;
  const ushort* Bp = WT + (size_t)(n0 + srow) * K + skoff;

  const int wave = t >> 6, lane = t & 63;
  const int wm = (wave >> 1) << 6;  // 0 or 64
  const int wn = (wave & 1) << 6;
  const int quad = lane >> 4, l15 = lane & 15;

  f32x4 acc[4][4] = {};

  for (int k0 = 0; k0 < K; k0 += 32) {
    uint4 av0 = *(const uint4*)(Ap + k0);
    uint4 av1 = *(const uint4*)(Ap + k0 + 8);
    uint4 bv0 = *(const uint4*)(Bp + k0);
    uint4 bv1 = *(const uint4*)(Bp + k0 + 8);
    *(uint4*)&As[srow][skoff] = av0;
    *(uint4*)&As[srow][skoff + 8] = av1;
    *(uint4*)&Bs[srow][skoff] = bv0;
    *(uint4*)&Bs[srow][skoff + 8] = bv1;
    __syncthreads();

    bf16x8 af[4], bfr[4];
#pragma unroll
    for (int i = 0; i < 4; ++i) {
      af[i] = *(const bf16x8*)&As[wm + i * 16 + l15][quad * 8];
      bfr[i] = *(const bf16x8*)&Bs[wn + i * 16 + l15][quad * 8];
    }
#pragma unroll
    for (int i = 0; i < 4; ++i)
#pragma unroll
      for (int j = 0; j < 4; ++j)
        acc[i][j] = __builtin_amdgcn_mfma_f32_16x16x32_bf16(af[i], bfr[j],
                                                            acc[i][j], 0, 0, 0);
    __syncthreads();
  }

#pragma unroll
  for (int i = 0; i < 4; ++i) {
#pragma unroll
    for (int j = 0; j < 4; ++j) {
      const int col = n0 + wn + j * 16 + l15;
      float bv = HASBIAS ? bias[col] : 0.0f;
#pragma unroll
      for (int r = 0; r < 4; ++r) {
        const int row = m0 + wm + i * 16 + quad * 4 + r;
        float c = acc[i][j][r];
        if (HASBIAS) c += bv;
        if (RELU) c = fmaxf(c, 0.0f);
        if (GATEMUL) c *= gate[(size_t)row * N + col];
        if (OUTBF16)
          ((ushort*)Cout)[(size_t)row * N + col] = f2bf(c);
        else
          ((float*)Cout)[(size_t)row * N + col] = c;
      }
    }
  }
}

// ---------------------------------------------------------------------------
extern "C" void kernel_launch(void* const* d_in, const int* in_sizes, int n_in,
                              void* d_out, int out_size, void* d_ws, size_t ws_size,
                              hipStream_t stream) {
  const float* x    = (const float*)d_in[0];
  const float* vc   = (const float*)d_in[1];
  const float* e_sp = (const float*)d_in[2];
  const float* W1e  = (const float*)d_in[3];
  const float* b1e  = (const float*)d_in[4];
  const float* W2e  = (const float*)d_in[5];
  const float* b2e  = (const float*)d_in[6];
  const float* W1r  = (const float*)d_in[7];
  const float* b1r  = (const float*)d_in[8];
  const float* W2r  = (const float*)d_in[9];
  const float* b2r  = (const float*)d_in[10];
  float* out = (float*)d_out;  // fp32 output

  // Workspace layout (MiB offsets; ~88 MiB total, round 4 used ~97 OK):
  //   0      keys (512 B)
  //   4096   W1eT [H][D] bf16 (1 MiB) | +1M W2eT [C][H] | +2M W1rT | +3M W2rT
  //   +4M    compsT [D][C] bf16 (0.5 MiB)
  //   8M     x_bf [B][D] bf16 (16 MiB)  -- reused as conc_bf [B][C] after G3
  //   24M    h_bf [B][H] bf16 (32 MiB)  -- h then hr
  //   56M    eg   [B][C] f32  (32 MiB)  -- e_dyn -> gate (in-place)
  char* ws = (char*)d_ws;
  uint32_t* keys = (uint32_t*)ws;
  ushort* W1eT   = (ushort*)(ws + (1u << 12));
  ushort* W2eT   = (ushort*)(ws + (1u << 12) + (1u << 20));
  ushort* W1rT   = (ushort*)(ws + (1u << 12) + (2u << 20));
  ushort* W2rT   = (ushort*)(ws + (1u << 12) + (3u << 20));
  ushort* compsT = (ushort*)(ws + (1u << 12) + (4u << 20));
  ushort* x_bf   = (ushort*)(ws + (8u << 20));
  ushort* conc   = x_bf;
  ushort* h_bf   = (ushort*)(ws + (24u << 20));
  float*  eg     = (float*)(ws + (56u << 20));

  // 1. threefry step keys
  k_setup_keys<<<1, 64, 0, stream>>>(keys);
  // 2. input conversions
  k_cvt_x<<<(Bn * Dn / 4) / 256, 256, 0, stream>>>(x, x_bf);
  k_transpose_cvt<<<(Dn * Hn) / 256, 256, 0, stream>>>(W1e, W1eT, Hn, Dn);
  k_transpose_cvt<<<(Hn * Cn) / 256, 256, 0, stream>>>(W2e, W2eT, Cn, Hn);
  k_transpose_cvt<<<(Dn * Hn) / 256, 256, 0, stream>>>(W1r, W1rT, Hn, Dn);
  k_transpose_cvt<<<(Hn * Cn) / 256, 256, 0, stream>>>(W2r, W2rT, Cn, Hn);
  // 3. static component mask (transposed, bf16)
  k_static_mask<<<(Cn * Dn) / 256, 256, 0, stream>>>(vc, e_sp, keys, compsT);
  // 4. h = relu(x @ W1e + b1e)            [bf16]
  k_gemm_mfma<true, true, false, true><<<dim3(Hn / 128, Bn / 128), 256, 0, stream>>>(
      x_bf, W1eT, b1e, nullptr, h_bf, Bn, Hn, Dn);
  // 5. e_dyn = h @ W2e + b2e              [f32]
  k_gemm_mfma<false, true, false, false><<<dim3(Cn / 128, Bn / 128), 256, 0, stream>>>(
      h_bf, W2eT, b2e, nullptr, eg, Bn, Cn, Hn);
  // 6. gate = langevin(e_dyn) in-place
  k_dyn_gate<<<(Bn * Cn) / 256, 256, 0, stream>>>(eg, keys + 64);
  // 7. hr = relu(x @ W1r + b1r)           [bf16, reuse h]
  k_gemm_mfma<true, true, false, true><<<dim3(Hn / 128, Bn / 128), 256, 0, stream>>>(
      x_bf, W1rT, b1r, nullptr, h_bf, Bn, Hn, Dn);
  // 8. conc = (hr @ W2r + b2r) * gate     [bf16, into x_bf region]
  k_gemm_mfma<false, true, true, true><<<dim3(Cn / 128, Bn / 128), 256, 0, stream>>>(
      h_bf, W2rT, b2r, eg, conc, Bn, Cn, Hn);
  // 9. out = conc @ comps                 [f32 to d_out]
  k_gemm_mfma<false, false, false, false><<<dim3(Dn / 128, Bn / 128), 256, 0, stream>>>(
      conc, compsT, nullptr, nullptr, out, Bn, Dn, Cn);
}

// Round 6
// 865.282 us; speedup vs baseline: 2.0948x; 1.0302x over previous
//
#include <hip/hip_runtime.h>
#include <hip/hip_bf16.h>
#include <stdint.h>

// Problem dims
#define Bn 16384
#define Cn 512
#define Dn 512
#define Hn 1024

typedef __attribute__((ext_vector_type(8))) short bf16x8;   // 8 bf16 (4 VGPRs)
typedef __attribute__((ext_vector_type(4))) float f32x4;    // MFMA accum

// f32 -> bf16 RTNE (manual; inputs are finite)
__device__ __forceinline__ ushort f2bf(float f) {
  uint32_t u = __float_as_uint(f);
  return (ushort)((u + 0x7fffu + ((u >> 16) & 1u)) >> 16);
}

// ---------------------------------------------------------------------------
// JAX threefry2x32 (20 rounds), PARTITIONABLE semantics (verified round 4)
// rotl forced to single v_alignbit_b32 via the clang rotate builtin.
// ---------------------------------------------------------------------------
__device__ __forceinline__ uint32_t rotl32(uint32_t v, int s) {
  return __builtin_rotateleft32(v, (uint32_t)s);
}

__device__ __forceinline__ void threefry2x32(uint32_t k0, uint32_t k1,
                                             uint32_t x0, uint32_t x1,
                                             uint32_t& o0, uint32_t& o1) {
  const uint32_t k2 = k0 ^ k1 ^ 0x1BD11BDAu;
  x0 += k0; x1 += k1;
#define TFR(r) { x0 += x1; x1 = rotl32(x1, (r)); x1 ^= x0; }
  TFR(13) TFR(15) TFR(26) TFR(6)   x0 += k1; x1 += k2 + 1u;
  TFR(17) TFR(29) TFR(16) TFR(24)  x0 += k2; x1 += k0 + 2u;
  TFR(13) TFR(15) TFR(26) TFR(6)   x0 += k0; x1 += k1 + 3u;
  TFR(17) TFR(29) TFR(16) TFR(24)  x0 += k1; x1 += k2 + 4u;
  TFR(13) TFR(15) TFR(26) TFR(6)   x0 += k2; x1 += k0 + 5u;
#undef TFR
  o0 = x0; o1 = x1;
}

// bits -> uniform[-0.99999994, 1) -> sqrt(2)*erfinv (XLA/Giles f32 polynomial)
__device__ __forceinline__ float bits_to_normal(uint32_t bits) {
  float f = __uint_as_float((bits >> 9) | 0x3f800000u) - 1.0f;  // [0,1)
  float x = f * 2.0f - 0x1.fffffep-1f;
  float w = -__logf(1.0f - x * x);
  float p;
  if (w < 5.0f) {
    w -= 2.5f;
    p =            2.81022636e-08f;
    p = fmaf(p, w, 3.43273939e-07f);
    p = fmaf(p, w, -3.5233877e-06f);
    p = fmaf(p, w, -4.39150654e-06f);
    p = fmaf(p, w, 0.00021858087f);
    p = fmaf(p, w, -0.00125372503f);
    p = fmaf(p, w, -0.00417768164f);
    p = fmaf(p, w, 0.246640727f);
    p = fmaf(p, w, 1.50140941f);
  } else {
    w = sqrtf(w) - 3.0f;
    p =            -0.000200214257f;
    p = fmaf(p, w, 0.000100950558f);
    p = fmaf(p, w, 0.00134934322f);
    p = fmaf(p, w, -0.00367342844f);
    p = fmaf(p, w, 0.00573950773f);
    p = fmaf(p, w, -0.0076224613f);
    p = fmaf(p, w, 0.00943887047f);
    p = fmaf(p, w, 1.00167406f);
    p = fmaf(p, w, 2.83297682f);
  }
  return 0x1.6a09e6p+0f * (p * x);  // sqrt(2) * erfinv(x)
}

// 32-step Langevin chain, single element (used by static mask)
__device__ __forceinline__ float langevin_gate(float e, const uint32_t* __restrict__ keys,
                                               uint32_t j) {
  float u = 0.0f;
#pragma unroll 1
  for (int t = 0; t < 32; ++t) {
    uint32_t o0, o1;
    threefry2x32(keys[2 * t], keys[2 * t + 1], 0u, j, o0, o1);
    float n = bits_to_normal(o0 ^ o1);
    u = (u - 0.05f * (u + e)) + 0.1f * n;
  }
  return 1.0f / (1.0f + __expf(u));  // sigmoid(-u)
}

// 32-step Langevin chain, 4 elements per thread (counters j0..j0+3).
// Same per-element arithmetic as langevin_gate — bit-identical results.
__device__ __forceinline__ void langevin_gate4(float4& e4,
                                               const uint32_t* __restrict__ keys,
                                               uint32_t j0) {
  float u0 = 0.0f, u1 = 0.0f, u2 = 0.0f, u3 = 0.0f;
#pragma unroll 2
  for (int t = 0; t < 32; ++t) {
    const uint32_t K0 = keys[2 * t], K1 = keys[2 * t + 1];
    uint32_t a0, b0, a1, b1, a2, b2, a3, b3;
    threefry2x32(K0, K1, 0u, j0 + 0u, a0, b0);
    threefry2x32(K0, K1, 0u, j0 + 1u, a1, b1);
    threefry2x32(K0, K1, 0u, j0 + 2u, a2, b2);
    threefry2x32(K0, K1, 0u, j0 + 3u, a3, b3);
    float n0 = bits_to_normal(a0 ^ b0);
    float n1 = bits_to_normal(a1 ^ b1);
    float n2 = bits_to_normal(a2 ^ b2);
    float n3 = bits_to_normal(a3 ^ b3);
    u0 = (u0 - 0.05f * (u0 + e4.x)) + 0.1f * n0;
    u1 = (u1 - 0.05f * (u1 + e4.y)) + 0.1f * n1;
    u2 = (u2 - 0.05f * (u2 + e4.z)) + 0.1f * n2;
    u3 = (u3 - 0.05f * (u3 + e4.w)) + 0.1f * n3;
  }
  e4.x = 1.0f / (1.0f + __expf(u0));
  e4.y = 1.0f / (1.0f + __expf(u1));
  e4.z = 1.0f / (1.0f + __expf(u2));
  e4.w = 1.0f / (1.0f + __expf(u3));
}

// keys[0..63] = static-mask step keys; keys[64..127] = dynamic-gate step keys
__global__ void k_setup_keys(uint32_t* __restrict__ keys) {
  if (threadIdx.x != 0 || blockIdx.x != 0) return;
  uint32_t k1w0, k1w1, k2w0, k2w1;
  threefry2x32(0u, 42u, 0u, 0u, k1w0, k1w1);
  threefry2x32(0u, 42u, 0u, 1u, k2w0, k2w1);
  for (uint32_t t = 0; t < 32; ++t) {
    uint32_t w0, w1;
    threefry2x32(k1w0, k1w1, 0u, t, w0, w1);
    keys[2 * t] = w0; keys[2 * t + 1] = w1;
    threefry2x32(k2w0, k2w1, 0u, t, w0, w1);
    keys[64 + 2 * t] = w0; keys[64 + 2 * t + 1] = w1;
  }
}

// compsT[d*C + c] = bf16(|vc[c*D+d]| * gate(e_sp[c*D+d]))   (coalesced stores)
__global__ __launch_bounds__(256) void k_static_mask(
    const float* __restrict__ vc, const float* __restrict__ e_sp,
    const uint32_t* __restrict__ keys, ushort* __restrict__ compsT) {
  uint32_t j = blockIdx.x * 256 + threadIdx.x;  // j = d*C + c
  uint32_t c = j & (Cn - 1), d = j >> 9;        // C = 512 = 2^9
  uint32_t ridx = c * Dn + d;                   // flat index in e_sp / vc
  float g = langevin_gate(e_sp[ridx], keys, ridx);
  compsT[j] = f2bf(fabsf(vc[ridx]) * g);
}

// in-place f32: eg[4q..4q+3] (= e_dyn) -> gate,  4 elements per thread
__global__ __launch_bounds__(256) void k_dyn_gate(
    float4* __restrict__ eg, const uint32_t* __restrict__ keys) {
  uint32_t q = blockIdx.x * 256 + threadIdx.x;
  float4 e4 = eg[q];
  langevin_gate4(e4, keys, 4u * q);
  eg[q] = e4;
}

// ---------------------------------------------------------------------------
// Conversion kernels (fp32 inputs -> bf16 workspace)
// ---------------------------------------------------------------------------
__global__ __launch_bounds__(256) void k_cvt_x(const float* __restrict__ in,
                                               ushort* __restrict__ out) {
  int i = (blockIdx.x * 256 + threadIdx.x) * 4;
  float4 v = *(const float4*)(in + i);
  ushort4 o = make_ushort4(f2bf(v.x), f2bf(v.y), f2bf(v.z), f2bf(v.w));
  *(ushort4*)(out + i) = o;
}

// out[n*KO + k] = bf16(in[k*NO + n]);  in is [KO][NO], out is [NO][KO]
__global__ __launch_bounds__(256) void k_transpose_cvt(
    const float* __restrict__ in, ushort* __restrict__ out, int NO, int KO) {
  int o = blockIdx.x * 256 + threadIdx.x;
  int n = o / KO, k = o % KO;  // KO is a power of two
  out[o] = f2bf(in[(size_t)k * NO + n]);
}

// ---------------------------------------------------------------------------
// bf16 MFMA GEMM: C[M,N] = epi(A[M,K] @ W[K,N]),  W given transposed WT[N][K].
// 128x128 tile, BK=32, 256 threads = 4 waves (2x2 of 64x64), 4x4 16x16 MFMA
// tiles per wave, f32 accum.  (verified round 5)
// ---------------------------------------------------------------------------
template <bool RELU, bool HASBIAS, bool GATEMUL, bool OUTBF16>
__global__ __launch_bounds__(256) void k_gemm_mfma(
    const ushort* __restrict__ A,    // [M][K] bf16
    const ushort* __restrict__ WT,   // [N][K] bf16
    const float* __restrict__ bias,  // [N] f32
    const float* __restrict__ gate,  // [M][N] f32
    void* __restrict__ Cout, int M, int N, int K) {
  __shared__ ushort As[128][40];  // +8 pad: 80 B rows -> 2-way banks (free)
  __shared__ ushort Bs[128][40];

  const int t = threadIdx.x;
  const int m0 = blockIdx.y * 128, n0 = blockIdx.x * 128;

  const int srow = t >> 1;
  const int skoff = (t & 1) << 4;  // 0 or 16
  const ushort* Ap = A + (size_t)(m0 + srow) * K + skoff;
  const ushort* Bp = WT + (size_t)(n0 + srow) * K + skoff;

  const int wave = t >> 6, lane = t & 63;
  const int wm = (wave >> 1) << 6;  // 0 or 64
  const int wn = (wave & 1) << 6;
  const int quad = lane >> 4, l15 = lane & 15;

  f32x4 acc[4][4] = {};

  for (int k0 = 0; k0 < K; k0 += 32) {
    uint4 av0 = *(const uint4*)(Ap + k0);
    uint4 av1 = *(const uint4*)(Ap + k0 + 8);
    uint4 bv0 = *(const uint4*)(Bp + k0);
    uint4 bv1 = *(const uint4*)(Bp + k0 + 8);
    *(uint4*)&As[srow][skoff] = av0;
    *(uint4*)&As[srow][skoff + 8] = av1;
    *(uint4*)&Bs[srow][skoff] = bv0;
    *(uint4*)&Bs[srow][skoff + 8] = bv1;
    __syncthreads();

    bf16x8 af[4], bfr[4];
#pragma unroll
    for (int i = 0; i < 4; ++i) {
      af[i] = *(const bf16x8*)&As[wm + i * 16 + l15][quad * 8];
      bfr[i] = *(const bf16x8*)&Bs[wn + i * 16 + l15][quad * 8];
    }
#pragma unroll
    for (int i = 0; i < 4; ++i)
#pragma unroll
      for (int j = 0; j < 4; ++j)
        acc[i][j] = __builtin_amdgcn_mfma_f32_16x16x32_bf16(af[i], bfr[j],
                                                            acc[i][j], 0, 0, 0);
    __syncthreads();
  }

#pragma unroll
  for (int i = 0; i < 4; ++i) {
#pragma unroll
    for (int j = 0; j < 4; ++j) {
      const int col = n0 + wn + j * 16 + l15;
      float bv = HASBIAS ? bias[col] : 0.0f;
#pragma unroll
      for (int r = 0; r < 4; ++r) {
        const int row = m0 + wm + i * 16 + quad * 4 + r;
        float c = acc[i][j][r];
        if (HASBIAS) c += bv;
        if (RELU) c = fmaxf(c, 0.0f);
        if (GATEMUL) c *= gate[(size_t)row * N + col];
        if (OUTBF16)
          ((ushort*)Cout)[(size_t)row * N + col] = f2bf(c);
        else
          ((float*)Cout)[(size_t)row * N + col] = c;
      }
    }
  }
}

// ---------------------------------------------------------------------------
extern "C" void kernel_launch(void* const* d_in, const int* in_sizes, int n_in,
                              void* d_out, int out_size, void* d_ws, size_t ws_size,
                              hipStream_t stream) {
  const float* x    = (const float*)d_in[0];
  const float* vc   = (const float*)d_in[1];
  const float* e_sp = (const float*)d_in[2];
  const float* W1e  = (const float*)d_in[3];
  const float* b1e  = (const float*)d_in[4];
  const float* W2e  = (const float*)d_in[5];
  const float* b2e  = (const float*)d_in[6];
  const float* W1r  = (const float*)d_in[7];
  const float* b1r  = (const float*)d_in[8];
  const float* W2r  = (const float*)d_in[9];
  const float* b2r  = (const float*)d_in[10];
  float* out = (float*)d_out;  // fp32 output

  // Workspace layout (~88 MiB total):
  //   0      keys (512 B)
  //   4096   W1eT | +1M W2eT | +2M W1rT | +3M W2rT   (bf16, transposed)
  //   +4M    compsT [D][C] bf16
  //   8M     x_bf [B][D] bf16 (16 MiB)  -- reused as conc_bf [B][C]
  //   24M    h_bf [B][H] bf16 (32 MiB)  -- h then hr
  //   56M    eg   [B][C] f32  (32 MiB)  -- e_dyn -> gate (in-place)
  char* ws = (char*)d_ws;
  uint32_t* keys = (uint32_t*)ws;
  ushort* W1eT   = (ushort*)(ws + (1u << 12));
  ushort* W2eT   = (ushort*)(ws + (1u << 12) + (1u << 20));
  ushort* W1rT   = (ushort*)(ws + (1u << 12) + (2u << 20));
  ushort* W2rT   = (ushort*)(ws + (1u << 12) + (3u << 20));
  ushort* compsT = (ushort*)(ws + (1u << 12) + (4u << 20));
  ushort* x_bf   = (ushort*)(ws + (8u << 20));
  ushort* conc   = x_bf;
  ushort* h_bf   = (ushort*)(ws + (24u << 20));
  float*  eg     = (float*)(ws + (56u << 20));

  // 1. threefry step keys
  k_setup_keys<<<1, 64, 0, stream>>>(keys);
  // 2. input conversions
  k_cvt_x<<<(Bn * Dn / 4) / 256, 256, 0, stream>>>(x, x_bf);
  k_transpose_cvt<<<(Dn * Hn) / 256, 256, 0, stream>>>(W1e, W1eT, Hn, Dn);
  k_transpose_cvt<<<(Hn * Cn) / 256, 256, 0, stream>>>(W2e, W2eT, Cn, Hn);
  k_transpose_cvt<<<(Dn * Hn) / 256, 256, 0, stream>>>(W1r, W1rT, Hn, Dn);
  k_transpose_cvt<<<(Hn * Cn) / 256, 256, 0, stream>>>(W2r, W2rT, Cn, Hn);
  // 3. static component mask (transposed, bf16)
  k_static_mask<<<(Cn * Dn) / 256, 256, 0, stream>>>(vc, e_sp, keys, compsT);
  // 4. h = relu(x @ W1e + b1e)            [bf16]
  k_gemm_mfma<true, true, false, true><<<dim3(Hn / 128, Bn / 128), 256, 0, stream>>>(
      x_bf, W1eT, b1e, nullptr, h_bf, Bn, Hn, Dn);
  // 5. e_dyn = h @ W2e + b2e              [f32]
  k_gemm_mfma<false, true, false, false><<<dim3(Cn / 128, Bn / 128), 256, 0, stream>>>(
      h_bf, W2eT, b2e, nullptr, eg, Bn, Cn, Hn);
  // 6. gate = langevin(e_dyn) in-place (4 elems/thread)
  k_dyn_gate<<<(Bn * Cn / 4) / 256, 256, 0, stream>>>((float4*)eg, keys + 64);
  // 7. hr = relu(x @ W1r + b1r)           [bf16, reuse h]
  k_gemm_mfma<true, true, false, true><<<dim3(Hn / 128, Bn / 128), 256, 0, stream>>>(
      x_bf, W1rT, b1r, nullptr, h_bf, Bn, Hn, Dn);
  // 8. conc = (hr @ W2r + b2r) * gate     [bf16, into x_bf region]
  k_gemm_mfma<false, true, true, true><<<dim3(Cn / 128, Bn / 128), 256, 0, stream>>>(
      h_bf, W2rT, b2r, eg, conc, Bn, Cn, Hn);
  // 9. out = conc @ comps                 [f32 to d_out]
  k_gemm_mfma<false, false, false, false><<<dim3(Dn / 128, Bn / 128), 256, 0, stream>>>(
      conc, compsT, nullptr, nullptr, out, Bn, Dn, Cn);
}